// Round 6
// baseline (2864.226 us; speedup 1.0000x reference)
//
#include <hip/hip_runtime.h>

// Problem: VQ-VAE codebook. z [32,256,32,32] f32, emb [8192,256] f32.
// Outputs concatenated in d_out (f32): z_q [8388608], idx [32768] (as float), loss [1].
//
// Scratch layout inside d_out's z_q region (consumed before k_out overwrites it):
//   [0 .. 2097152)        embT  (256 x 8192)   transposed codebook
//   [2097152 .. 2105344)  se    (8192)         ||e_k||^2
//   [2105344 .. 2138112)  sz    (32768)        ||z_n||^2
#define ZQ_OFF   0
#define EMBT_OFF 0
#define SE_OFF   2097152
#define SZ_OFF   2105344
#define IDX_OFF  8388608
#define LOSS_OFF 8421376

// ---- transpose emb -> embT[d][k] (coalesced writes, scattered reads; 8 MB, tiny)
__global__ void k_prep_transpose(const float* __restrict__ emb, float* __restrict__ embT) {
    int u = blockIdx.x * 256 + threadIdx.x;      // 0 .. 2M, grid = 8192 blocks
    int d = u >> 13;
    int k = u & 8191;
    embT[u] = emb[(size_t)k * 256 + d];
}

// ---- se[k] = sum(emb[k]^2)  (order-insensitive; wave per code, butterfly reduce)
__global__ void k_se(const float* __restrict__ emb, float* __restrict__ se) {
    int w    = (blockIdx.x * 256 + threadIdx.x) >> 6;   // code id
    int lane = threadIdx.x & 63;
    float4 v = *(const float4*)(emb + (size_t)w * 256 + lane * 4);
    float s = v.x * v.x + v.y * v.y + v.z * v.z + v.w * v.w;
    #pragma unroll
    for (int off = 1; off < 64; off <<= 1) s += __shfl_xor(s, off);
    if (lane == 0) se[w] = s;
}

// ---- sz[n] = sum over c of z[b][c][hw]^2 (order-insensitive: same-binade shift invariance)
__global__ void k_sz(const float* __restrict__ z, float* __restrict__ sz) {
    int n  = blockIdx.x * 256 + threadIdx.x;  // grid = 128 blocks
    int b  = n >> 10, hw = n & 1023;
    const float* zp = z + (size_t)b * 262144 + hw;
    float acc = 0.f;
    #pragma unroll 8
    for (int c = 0; c < 256; ++c) { float v = zp[(size_t)c << 10]; acc += v * v; }
    sz[n] = acc;
}

// ---- main: exact-f32-replica distance + argmin. NO LDS in the main loop.
// 256 thr = 4 waves = (2 row-groups x 2 code-groups); 32 rows/block; grid 1024 (=4 blk/CU).
// Per thread: R=16 rows x C=4 codes (acc 64 VGPR). z read directly from global with
// wave-uniform float4 loads (broadcast; z tile is L1/L2-resident, 32 KB live set).
// ef read from global (L2/L3-resident embT) with a 2-d register double-buffer.
// d_nk = fl( fl(sz_n + se_k) - 2*m_nk ),  m = sequential fmaf chain over d=0..255 (BLAS order)
__global__ __launch_bounds__(256, 4) void k_main(
    const float* __restrict__ z, const float* __restrict__ embT,
    const float* __restrict__ se, const float* __restrict__ sz,
    float* __restrict__ idxf, float* __restrict__ lossslot) {
    __shared__ float szs[32];
    __shared__ float cwd[2][2][16];       // [codegrp][rowgrp][row] best distance
    __shared__ int   cwk[2][2][16];       // matching code id
    const int tid = threadIdx.x;
    const int blk = blockIdx.x;           // grid = 1024
    const int n0  = blk * 32;
    const int b   = n0 >> 10, hw0 = n0 & 1023;

    if (tid < 32) szs[tid] = sz[n0 + tid];
    if (tid < 64) { (&cwd[0][0][0])[tid] = 3.4e38f; (&cwk[0][0][0])[tid] = 0; }
    __syncthreads();

    const int w   = tid >> 6;     // wave 0..3
    const int rg  = w & 1;        // row group: rows rg*16 .. rg*16+15
    const int cgr = w >> 1;       // code group within each 512-code tile
    const int j   = tid & 63;     // lane -> 4 codes
    const int r0  = rg * 16;

    // wave-uniform base of this wave's 16 z rows (advance by 1024 floats per d)
    const float* zb = z + (size_t)b * 262144 + hw0 + r0;

    for (int tile = 0; tile < 16; ++tile) {
        const int c0 = tile * 512 + cgr * 256 + j * 4;
        const float* ep = embT + c0;
        float acc[16][4];
        #pragma unroll
        for (int rr = 0; rr < 16; ++rr)
            #pragma unroll
            for (int c = 0; c < 4; ++c) acc[rr][c] = 0.f;

        // ef double-buffer: hold d and d+1, prefetch d+2 and d+3
        float4 efA0 = *(const float4*)(ep);
        float4 efA1 = *(const float4*)(ep + 8192);
        const float* zp = zb;

        #pragma unroll 2
        for (int db = 0; db < 128; ++db) {             // 2 d per iter, d ascending
            const int dn = 2 * db + 2;
            // prefetch ef for d+2, d+3 (last iter reads in-buffer garbage, never used)
            float4 efB0 = *(const float4*)(ep + (size_t)dn * 8192);
            float4 efB1 = *(const float4*)(ep + (size_t)(dn + 1) * 8192);

            // d = 2*db : z rows via uniform-address broadcast loads
            {
                float4 zv[4];
                #pragma unroll
                for (int i = 0; i < 4; ++i)
                    zv[i] = *(const float4*)(zp + i * 4);
                #pragma unroll
                for (int i = 0; i < 4; ++i) {
                    #pragma unroll
                    for (int q = 0; q < 4; ++q) {
                        const float zx = ((const float*)&zv[i])[q];
                        const int rr = i * 4 + q;
                        acc[rr][0] = fmaf(zx, efA0.x, acc[rr][0]);
                        acc[rr][1] = fmaf(zx, efA0.y, acc[rr][1]);
                        acc[rr][2] = fmaf(zx, efA0.z, acc[rr][2]);
                        acc[rr][3] = fmaf(zx, efA0.w, acc[rr][3]);
                    }
                }
            }
            zp += 1024;
            // d = 2*db + 1
            {
                float4 zv[4];
                #pragma unroll
                for (int i = 0; i < 4; ++i)
                    zv[i] = *(const float4*)(zp + i * 4);
                #pragma unroll
                for (int i = 0; i < 4; ++i) {
                    #pragma unroll
                    for (int q = 0; q < 4; ++q) {
                        const float zx = ((const float*)&zv[i])[q];
                        const int rr = i * 4 + q;
                        acc[rr][0] = fmaf(zx, efA1.x, acc[rr][0]);
                        acc[rr][1] = fmaf(zx, efA1.y, acc[rr][1]);
                        acc[rr][2] = fmaf(zx, efA1.z, acc[rr][2]);
                        acc[rr][3] = fmaf(zx, efA1.w, acc[rr][3]);
                    }
                }
            }
            zp += 1024;
            efA0 = efB0; efA1 = efB1;
        }

        // epilogue: dq = fl( fl(sz+se) - 2m ); per-row argmin over this tile's 256 codes
        const float4 se4 = *(const float4*)(se + c0);
        #pragma unroll
        for (int rr = 0; rr < 16; ++rr) {
            const float szv = szs[r0 + rr];
            float bd = 3.4e38f; int bk = 0;
            #pragma unroll
            for (int c = 0; c < 4; ++c) {               // ascending c; strict < keeps first
                float A  = szv + ((const float*)&se4)[c];
                float dq = A - 2.0f * acc[rr][c];
                if (dq < bd) { bd = dq; bk = c0 + c; }
            }
            #pragma unroll
            for (int off = 1; off < 64; off <<= 1) {    // full tie-break: lowest k
                float od = __shfl_xor(bd, off);
                int   ok = __shfl_xor(bk, off);
                if (od < bd || (od == bd && ok < bk)) { bd = od; bk = ok; }
            }
            if (j == 0) {
                float pd = cwd[cgr][rg][rr]; int pk = cwk[cgr][rg][rr];
                if (bd < pd || (bd == pd && bk < pk)) {
                    cwd[cgr][rg][rr] = bd; cwk[cgr][rg][rr] = bk;
                }
            }
        }
    }
    __syncthreads();
    // merge the 2 code-groups per row with full tie-break (code ranges interleave)
    if (tid < 32) {
        const int rgx = tid >> 4, row = tid & 15;
        float d0 = cwd[0][rgx][row]; int k0 = cwk[0][rgx][row];
        float d1 = cwd[1][rgx][row]; int k1 = cwk[1][rgx][row];
        if (d1 < d0 || (d1 == d0 && k1 < k0)) { d0 = d1; k0 = k1; }
        idxf[n0 + rgx * 16 + row] = (float)k0;
    }
    if (blk == 0 && tid == 0) *lossslot = 0.f;   // init loss accumulator (runs before k_out)
}

// ---- z_q (STE-exact) + loss partial sums
__global__ void k_out(const float* __restrict__ z, const float* __restrict__ emb,
                      const float* __restrict__ idxf, float* __restrict__ zq,
                      float* __restrict__ lossslot) {
    int u   = blockIdx.x * 256 + threadIdx.x;   // grid = 8192 blocks (2M threads)
    int cc4 = u >> 15;                          // 0..63 (uniform per block)
    int n   = u & 32767;
    int b   = n >> 10, hw = n & 1023;
    int k   = (int)idxf[n];
    const float4 q4 = *(const float4*)(emb + (size_t)k * 256 + cc4 * 4);
    float ls = 0.f;
    #pragma unroll
    for (int c = 0; c < 4; ++c) {
        size_t zi = (size_t)b * 262144 + (size_t)(cc4 * 4 + c) * 1024 + hw;
        float zv   = z[zi];
        float qv   = ((const float*)&q4)[c];
        float diff = qv - zv;        // fl(q - z)
        zq[zi]     = zv + diff;      // fl(z + fl(q - z))  == reference STE output
        ls += diff * diff;
    }
    #pragma unroll
    for (int off = 1; off < 64; off <<= 1) ls += __shfl_xor(ls, off);
    if ((threadIdx.x & 63) == 0) atomicAdd(lossslot, ls);
}

__global__ void k_fin(float* __restrict__ lossslot) {
    float S = *lossslot;
    float m = S / 8388608.0f;        // /2^23 exact scaling
    *lossslot = m + 0.25f * m;       // fl(m1 + fl(beta*m2)), m1==m2
}

extern "C" void kernel_launch(void* const* d_in, const int* in_sizes, int n_in,
                              void* d_out, int out_size, void* d_ws, size_t ws_size,
                              hipStream_t stream) {
    const float* z   = (const float*)d_in[0];
    const float* emb = (const float*)d_in[1];
    float* out  = (float*)d_out;
    float* embT = out + EMBT_OFF;
    float* se   = out + SE_OFF;
    float* sz   = out + SZ_OFF;
    float* idxf = out + IDX_OFF;
    float* loss = out + LOSS_OFF;

    k_prep_transpose<<<8192, 256, 0, stream>>>(emb, embT);
    k_se<<<2048, 256, 0, stream>>>(emb, se);
    k_sz<<<128, 256, 0, stream>>>(z, sz);
    k_main<<<1024, 256, 0, stream>>>(z, embT, se, sz, idxf, loss);
    k_out<<<8192, 256, 0, stream>>>(z, emb, idxf, out + ZQ_OFF, loss);
    k_fin<<<1, 1, 0, stream>>>(loss);
}

// Round 7
// 2286.763 us; speedup vs baseline: 1.2525x; 1.2525x over previous
//
#include <hip/hip_runtime.h>

// Problem: VQ-VAE codebook. z [32,256,32,32] f32, emb [8192,256] f32.
// Outputs concatenated in d_out (f32): z_q [8388608], idx [32768] (as float), loss [1].
//
// Scratch layout inside d_out's z_q region (consumed before k_out overwrites it):
//   [0 .. 2097152)        embT  (256 x 8192)   transposed codebook
//   [2097152 .. 2105344)  se    (8192)         ||e_k||^2
//   [2105344 .. 2138112)  sz    (32768)        ||z_n||^2
#define ZQ_OFF   0
#define EMBT_OFF 0
#define SE_OFF   2097152
#define SZ_OFF   2105344
#define IDX_OFF  8388608
#define LOSS_OFF 8421376

// ---- transpose emb -> embT[d][k] (coalesced writes, scattered reads; 8 MB, tiny)
__global__ void k_prep_transpose(const float* __restrict__ emb, float* __restrict__ embT) {
    int u = blockIdx.x * 256 + threadIdx.x;      // 0 .. 2M, grid = 8192 blocks
    int d = u >> 13;
    int k = u & 8191;
    embT[u] = emb[(size_t)k * 256 + d];
}

// ---- se[k] = sum(emb[k]^2)  (order-insensitive; wave per code, butterfly reduce)
__global__ void k_se(const float* __restrict__ emb, float* __restrict__ se) {
    int w    = (blockIdx.x * 256 + threadIdx.x) >> 6;   // code id
    int lane = threadIdx.x & 63;
    float4 v = *(const float4*)(emb + (size_t)w * 256 + lane * 4);
    float s = v.x * v.x + v.y * v.y + v.z * v.z + v.w * v.w;
    #pragma unroll
    for (int off = 1; off < 64; off <<= 1) s += __shfl_xor(s, off);
    if (lane == 0) se[w] = s;
}

// ---- sz[n] = sum over c of z[b][c][hw]^2 (order-insensitive: same-binade shift invariance)
__global__ void k_sz(const float* __restrict__ z, float* __restrict__ sz) {
    int n  = blockIdx.x * 256 + threadIdx.x;  // grid = 128 blocks
    int b  = n >> 10, hw = n & 1023;
    const float* zp = z + (size_t)b * 262144 + hw;
    float acc = 0.f;
    #pragma unroll 8
    for (int c = 0; c < 256; ++c) { float v = zp[(size_t)c << 10]; acc += v * v; }
    sz[n] = acc;
}

// 64 FMAs for one d: 8 rows (2 float4 z, broadcast) x 8 codes (2 float4 ef)
#define FMA_BLOCK(Z0, Z1, E0, E1) do {                                   \
    _Pragma("unroll")                                                     \
    for (int i_ = 0; i_ < 2; ++i_) {                                      \
        const float4 zv_ = (i_ == 0) ? (Z0) : (Z1);                       \
        _Pragma("unroll")                                                 \
        for (int q_ = 0; q_ < 4; ++q_) {                                  \
            const float zx_ = ((const float*)&zv_)[q_];                   \
            const int rr_ = i_ * 4 + q_;                                  \
            acc[rr_][0] = fmaf(zx_, (E0).x, acc[rr_][0]);                 \
            acc[rr_][1] = fmaf(zx_, (E0).y, acc[rr_][1]);                 \
            acc[rr_][2] = fmaf(zx_, (E0).z, acc[rr_][2]);                 \
            acc[rr_][3] = fmaf(zx_, (E0).w, acc[rr_][3]);                 \
            acc[rr_][4] = fmaf(zx_, (E1).x, acc[rr_][4]);                 \
            acc[rr_][5] = fmaf(zx_, (E1).y, acc[rr_][5]);                 \
            acc[rr_][6] = fmaf(zx_, (E1).z, acc[rr_][6]);                 \
            acc[rr_][7] = fmaf(zx_, (E1).w, acc[rr_][7]);                 \
        }                                                                 \
    }                                                                     \
} while (0)

// ---- main: exact-f32-replica distance + argmin.
// 256 thr = 4 waves; 32 rows/block; grid 1024 (= 4 blocks/CU at 33 KB LDS).
// Wave w owns rows w*8..w*8+7 (disjoint -> no cross-wave argmin merge). All waves share
// the 512-code tile range (lane j owns codes tile*512 + j*8..+7; 16 tiles) -> 4x ef L1 reuse.
// Per thread R=8 x C=8 -> per d only 2 broadcast ds_read_b128 per 64 FMAs (LDS pipe 0.75x).
// z and ef software-pipelined one d ahead with A/B register rotation.
// d_nk = fl( fl(sz_n + se_k) - 2*m_nk ),  m = sequential fmaf chain over d=0..255 (BLAS order)
__global__ __launch_bounds__(256, 4) void k_main(
    const float* __restrict__ z, const float* __restrict__ embT,
    const float* __restrict__ se, const float* __restrict__ sz,
    float* __restrict__ idxf, float* __restrict__ lossslot) {
    __shared__ float ztT[258][32];        // [d][row]; 2 pad rows absorb d+2 prefetch OOB
    __shared__ float szs[32];
    const int tid = threadIdx.x;
    const int blk = blockIdx.x;           // grid = 1024
    const int n0  = blk * 32;
    const int b   = n0 >> 10, hw0 = n0 & 1023;

    // stage z tile transposed: ztT[c][n]; coalesced global reads over n (2-way bank alias, free)
    {
        const int n  = tid & 31;
        const int cg = tid >> 5;                        // 0..7
        const float* zp = z + (size_t)b * 262144 + hw0 + n;
        #pragma unroll
        for (int cc = 0; cc < 256; cc += 8)
            ztT[cc + cg][n] = zp[(size_t)(cc + cg) << 10];
        if (tid < 32) szs[tid] = sz[n0 + tid];
    }
    __syncthreads();

    const int w  = tid >> 6;      // wave 0..3 -> rows w*8 .. w*8+7
    const int j  = tid & 63;      // lane -> 8 codes per tile
    const int r0 = w * 8;

    float bd[8]; int bk[8];
    #pragma unroll
    for (int rr = 0; rr < 8; ++rr) { bd[rr] = 3.4e38f; bk[rr] = 0; }

    for (int tile = 0; tile < 16; ++tile) {
        const int c0 = tile * 512 + j * 8;
        const float* ep = embT + c0;

        float acc[8][8];
        #pragma unroll
        for (int rr = 0; rr < 8; ++rr)
            #pragma unroll
            for (int c = 0; c < 8; ++c) acc[rr][c] = 0.f;

        // preload d=0 into A
        float4 zA0 = *(const float4*)&ztT[0][r0];
        float4 zA1 = *(const float4*)&ztT[0][r0 + 4];
        float4 eA0 = *(const float4*)(ep);
        float4 eA1 = *(const float4*)(ep + 4);

        for (int d = 0; d < 256; d += 2) {
            // load d+1 into B
            const float* e1p = ep + (size_t)(d + 1) * 8192;
            float4 eB0 = *(const float4*)(e1p);
            float4 eB1 = *(const float4*)(e1p + 4);
            float4 zB0 = *(const float4*)&ztT[d + 1][r0];
            float4 zB1 = *(const float4*)&ztT[d + 1][r0 + 4];
            // compute d (held in A)
            FMA_BLOCK(zA0, zA1, eA0, eA1);
            // load d+2 into A (d=254 reads ztT[256] pad / embT+2M: harmless, never used)
            const float* e2p = ep + (size_t)(d + 2) * 8192;
            eA0 = *(const float4*)(e2p);
            eA1 = *(const float4*)(e2p + 4);
            zA0 = *(const float4*)&ztT[d + 2][r0];
            zA1 = *(const float4*)&ztT[d + 2][r0 + 4];
            // compute d+1 (held in B)
            FMA_BLOCK(zB0, zB1, eB0, eB1);
        }

        // epilogue: dq = fl( fl(sz+se) - 2m ); codes ascending (c0..c0+7); strict < keeps first
        const float4 seA = *(const float4*)(se + c0);
        const float4 seB = *(const float4*)(se + c0 + 4);
        #pragma unroll
        for (int rr = 0; rr < 8; ++rr) {
            const float szv = szs[r0 + rr];
            #pragma unroll
            for (int c = 0; c < 8; ++c) {
                const float sek = (c < 4) ? ((const float*)&seA)[c]
                                          : ((const float*)&seB)[c - 4];
                float A  = szv + sek;
                float dq = A - 2.0f * acc[rr][c];
                if (dq < bd[rr]) { bd[rr] = dq; bk[rr] = c0 + c; }
            }
        }
    }

    // final: butterfly across 64 lanes per row (per-thread bests are ascending-k first-min);
    // tie-break lowest k
    #pragma unroll
    for (int rr = 0; rr < 8; ++rr) {
        float d = bd[rr]; int k = bk[rr];
        #pragma unroll
        for (int off = 1; off < 64; off <<= 1) {
            float od = __shfl_xor(d, off);
            int   ok = __shfl_xor(k, off);
            if (od < d || (od == d && ok < k)) { d = od; k = ok; }
        }
        if (j == 0) idxf[n0 + r0 + rr] = (float)k;
    }
    if (blk == 0 && tid == 0) *lossslot = 0.f;   // init loss accumulator (runs before k_out)
}

// ---- z_q (STE-exact) + loss partial sums
__global__ void k_out(const float* __restrict__ z, const float* __restrict__ emb,
                      const float* __restrict__ idxf, float* __restrict__ zq,
                      float* __restrict__ lossslot) {
    int u   = blockIdx.x * 256 + threadIdx.x;   // grid = 8192 blocks (2M threads)
    int cc4 = u >> 15;                          // 0..63 (uniform per block)
    int n   = u & 32767;
    int b   = n >> 10, hw = n & 1023;
    int k   = (int)idxf[n];
    const float4 q4 = *(const float4*)(emb + (size_t)k * 256 + cc4 * 4);
    float ls = 0.f;
    #pragma unroll
    for (int c = 0; c < 4; ++c) {
        size_t zi = (size_t)b * 262144 + (size_t)(cc4 * 4 + c) * 1024 + hw;
        float zv   = z[zi];
        float qv   = ((const float*)&q4)[c];
        float diff = qv - zv;        // fl(q - z)
        zq[zi]     = zv + diff;      // fl(z + fl(q - z))  == reference STE output
        ls += diff * diff;
    }
    #pragma unroll
    for (int off = 1; off < 64; off <<= 1) ls += __shfl_xor(ls, off);
    if ((threadIdx.x & 63) == 0) atomicAdd(lossslot, ls);
}

__global__ void k_fin(float* __restrict__ lossslot) {
    float S = *lossslot;
    float m = S / 8388608.0f;        // /2^23 exact scaling
    *lossslot = m + 0.25f * m;       // fl(m1 + fl(beta*m2)), m1==m2
}

extern "C" void kernel_launch(void* const* d_in, const int* in_sizes, int n_in,
                              void* d_out, int out_size, void* d_ws, size_t ws_size,
                              hipStream_t stream) {
    const float* z   = (const float*)d_in[0];
    const float* emb = (const float*)d_in[1];
    float* out  = (float*)d_out;
    float* embT = out + EMBT_OFF;
    float* se   = out + SE_OFF;
    float* sz   = out + SZ_OFF;
    float* idxf = out + IDX_OFF;
    float* loss = out + LOSS_OFF;

    k_prep_transpose<<<8192, 256, 0, stream>>>(emb, embT);
    k_se<<<2048, 256, 0, stream>>>(emb, se);
    k_sz<<<128, 256, 0, stream>>>(z, sz);
    k_main<<<1024, 256, 0, stream>>>(z, embT, se, sz, idxf, loss);
    k_out<<<8192, 256, 0, stream>>>(z, emb, idxf, out + ZQ_OFF, loss);
    k_fin<<<1, 1, 0, stream>>>(loss);
}

// Round 8
// 2162.138 us; speedup vs baseline: 1.3247x; 1.0576x over previous
//
#include <hip/hip_runtime.h>

// Problem: VQ-VAE codebook. z [32,256,32,32] f32, emb [8192,256] f32.
// Outputs concatenated in d_out (f32): z_q [8388608], idx [32768] (as float), loss [1].
//
// Scratch layout inside d_out's z_q region (consumed before k_out overwrites it):
//   [0 .. 2097152)        embT  (256 x 8192)   transposed codebook
//   [2097152 .. 2105344)  se    (8192)         ||e_k||^2
//   [2105344 .. 2138112)  sz    (32768)        ||z_n||^2
#define ZQ_OFF   0
#define EMBT_OFF 0
#define SE_OFF   2097152
#define SZ_OFF   2105344
#define IDX_OFF  8388608
#define LOSS_OFF 8421376

// ---- transpose emb -> embT[d][k] (coalesced writes, scattered reads; 8 MB, tiny)
__global__ void k_prep_transpose(const float* __restrict__ emb, float* __restrict__ embT) {
    int u = blockIdx.x * 256 + threadIdx.x;      // 0 .. 2M, grid = 8192 blocks
    int d = u >> 13;
    int k = u & 8191;
    embT[u] = emb[(size_t)k * 256 + d];
}

// ---- se[k] = sum(emb[k]^2)  (order-insensitive; wave per code, butterfly reduce)
__global__ void k_se(const float* __restrict__ emb, float* __restrict__ se) {
    int w    = (blockIdx.x * 256 + threadIdx.x) >> 6;   // code id
    int lane = threadIdx.x & 63;
    float4 v = *(const float4*)(emb + (size_t)w * 256 + lane * 4);
    float s = v.x * v.x + v.y * v.y + v.z * v.z + v.w * v.w;
    #pragma unroll
    for (int off = 1; off < 64; off <<= 1) s += __shfl_xor(s, off);
    if (lane == 0) se[w] = s;
}

// ---- sz[n] = sum over c of z[b][c][hw]^2 (order-insensitive: same-binade shift invariance)
__global__ void k_sz(const float* __restrict__ z, float* __restrict__ sz) {
    int n  = blockIdx.x * 256 + threadIdx.x;  // grid = 128 blocks
    int b  = n >> 10, hw = n & 1023;
    const float* zp = z + (size_t)b * 262144 + hw;
    float acc = 0.f;
    #pragma unroll 8
    for (int c = 0; c < 256; ++c) { float v = zp[(size_t)c << 10]; acc += v * v; }
    sz[n] = acc;
}

// 128 FMAs for one d: 16 rows (4 float4 z, broadcast) x 8 codes (2 float4 ef)
#define FMA_BLOCK(E0, E1) do {                                           \
    _Pragma("unroll")                                                     \
    for (int i_ = 0; i_ < 4; ++i_) {                                      \
        _Pragma("unroll")                                                 \
        for (int q_ = 0; q_ < 4; ++q_) {                                  \
            const float zx_ = ((const float*)&zv[i_])[q_];                \
            const int rr_ = i_ * 4 + q_;                                  \
            acc[rr_][0] = fmaf(zx_, (E0).x, acc[rr_][0]);                 \
            acc[rr_][1] = fmaf(zx_, (E0).y, acc[rr_][1]);                 \
            acc[rr_][2] = fmaf(zx_, (E0).z, acc[rr_][2]);                 \
            acc[rr_][3] = fmaf(zx_, (E0).w, acc[rr_][3]);                 \
            acc[rr_][4] = fmaf(zx_, (E1).x, acc[rr_][4]);                 \
            acc[rr_][5] = fmaf(zx_, (E1).y, acc[rr_][5]);                 \
            acc[rr_][6] = fmaf(zx_, (E1).z, acc[rr_][6]);                 \
            acc[rr_][7] = fmaf(zx_, (E1).w, acc[rr_][7]);                 \
        }                                                                 \
    }                                                                     \
} while (0)

// ---- main: exact-f32-replica distance + argmin.
// 256 thr = 4 waves; 16 rows/block; grid 2048 (8 blocks/CU demand, ~3 resident at VGPR cap).
// All waves cover all 16 rows (R=16/thread); waves split codes 4-ways within a 2048-code
// tile: wave w owns w*512..+511, lane j owns 8 codes. Per d: 4 broadcast ds_read_b128 (z)
// + 2 global float4 (ef) per 128 FMA -> L1 port 0.5, LDS pipe 0.75, FMA the only
// saturated pipe. ef double-buffered one d ahead. Per-tile argmin folded into LDS
// cwd/cwk (full lowest-k tie-break; no persistent best registers -> acc fits 3 waves/SIMD).
// d_nk = fl( fl(sz_n + se_k) - 2*m_nk ),  m = sequential fmaf chain over d=0..255 (BLAS order)
__global__ __launch_bounds__(256, 3) void k_main(
    const float* __restrict__ z, const float* __restrict__ embT,
    const float* __restrict__ se, const float* __restrict__ sz,
    float* __restrict__ idxf, float* __restrict__ lossslot) {
    __shared__ float ztT[256][16];        // [d][row]
    __shared__ float szs[16];
    __shared__ float cwd[4][16];          // [codegrp][row] best distance
    __shared__ int   cwk[4][16];          // matching code id
    const int tid = threadIdx.x;
    const int blk = blockIdx.x;           // grid = 2048
    const int n0  = blk * 16;
    const int b   = n0 >> 10, hw0 = n0 & 1023;

    // stage z tile transposed: ztT[c][n]; coalesced global reads over n;
    // LDS writes 2 lanes/bank (free)
    {
        const int n  = tid & 15;
        const int cg = tid >> 4;                        // 0..15
        const float* zp = z + (size_t)b * 262144 + hw0 + n;
        #pragma unroll
        for (int cc = 0; cc < 256; cc += 16)
            ztT[cc + cg][n] = zp[(size_t)(cc + cg) << 10];
        if (tid < 16) szs[tid] = sz[n0 + tid];
        if (tid < 64) { (&cwd[0][0])[tid] = 3.4e38f; (&cwk[0][0])[tid] = 0; }
    }
    __syncthreads();

    const int w = tid >> 6;       // wave 0..3 -> code quarter w*512 within each tile
    const int j = tid & 63;       // lane -> 8 codes

    for (int tile = 0; tile < 4; ++tile) {
        const int c0 = tile * 2048 + w * 512 + j * 8;
        const float* ep = embT + c0;

        float acc[16][8];
        #pragma unroll
        for (int rr = 0; rr < 16; ++rr)
            #pragma unroll
            for (int c = 0; c < 8; ++c) acc[rr][c] = 0.f;

        // preload ef d=0
        float4 eA0 = *(const float4*)(ep);
        float4 eA1 = *(const float4*)(ep + 4);

        #pragma unroll 2
        for (int d = 0; d < 256; ++d) {
            // prefetch ef d+1 (d=255 reads embT+2M = se region: valid mem, never used)
            const float* e1p = ep + (size_t)(d + 1) * 8192;
            float4 eB0 = *(const float4*)(e1p);
            float4 eB1 = *(const float4*)(e1p + 4);
            // z rows: broadcast LDS reads (wave-uniform address)
            float4 zv[4];
            #pragma unroll
            for (int i = 0; i < 4; ++i)
                zv[i] = *(const float4*)&ztT[d][i * 4];
            FMA_BLOCK(eA0, eA1);
            eA0 = eB0; eA1 = eB1;
        }

        // epilogue: dq = fl( fl(sz+se) - 2m ); codes ascending; strict < keeps first min
        const float4 seA = *(const float4*)(se + c0);
        const float4 seB = *(const float4*)(se + c0 + 4);
        #pragma unroll
        for (int rr = 0; rr < 16; ++rr) {
            const float szv = szs[rr];
            float bd = 3.4e38f; int bk = 0;
            #pragma unroll
            for (int c = 0; c < 8; ++c) {
                const float sek = (c < 4) ? ((const float*)&seA)[c]
                                          : ((const float*)&seB)[c - 4];
                float A  = szv + sek;
                float dq = A - 2.0f * acc[rr][c];
                if (dq < bd) { bd = dq; bk = c0 + c; }
            }
            // butterfly across 64 lanes; tie-break lowest k
            #pragma unroll
            for (int off = 1; off < 64; off <<= 1) {
                float od = __shfl_xor(bd, off);
                int   ok = __shfl_xor(bk, off);
                if (od < bd || (od == bd && ok < bk)) { bd = od; bk = ok; }
            }
            if (j == 0) {
                float pd = cwd[w][rr]; int pk = cwk[w][rr];
                if (bd < pd || (bd == pd && bk < pk)) { cwd[w][rr] = bd; cwk[w][rr] = bk; }
            }
        }
    }
    __syncthreads();
    // merge the 4 code-group partials per row with full (d,k) tie-break
    if (tid < 16) {
        float d = cwd[0][tid]; int k = cwk[0][tid];
        #pragma unroll
        for (int ww = 1; ww < 4; ++ww) {
            float od = cwd[ww][tid]; int ok = cwk[ww][tid];
            if (od < d || (od == d && ok < k)) { d = od; k = ok; }
        }
        idxf[n0 + tid] = (float)k;
    }
    if (blk == 0 && tid == 0) *lossslot = 0.f;   // init loss accumulator (runs before k_out)
}

// ---- z_q (STE-exact) + loss partial sums
__global__ void k_out(const float* __restrict__ z, const float* __restrict__ emb,
                      const float* __restrict__ idxf, float* __restrict__ zq,
                      float* __restrict__ lossslot) {
    int u   = blockIdx.x * 256 + threadIdx.x;   // grid = 8192 blocks (2M threads)
    int cc4 = u >> 15;                          // 0..63 (uniform per block)
    int n   = u & 32767;
    int b   = n >> 10, hw = n & 1023;
    int k   = (int)idxf[n];
    const float4 q4 = *(const float4*)(emb + (size_t)k * 256 + cc4 * 4);
    float ls = 0.f;
    #pragma unroll
    for (int c = 0; c < 4; ++c) {
        size_t zi = (size_t)b * 262144 + (size_t)(cc4 * 4 + c) * 1024 + hw;
        float zv   = z[zi];
        float qv   = ((const float*)&q4)[c];
        float diff = qv - zv;        // fl(q - z)
        zq[zi]     = zv + diff;      // fl(z + fl(q - z))  == reference STE output
        ls += diff * diff;
    }
    #pragma unroll
    for (int off = 1; off < 64; off <<= 1) ls += __shfl_xor(ls, off);
    if ((threadIdx.x & 63) == 0) atomicAdd(lossslot, ls);
}

__global__ void k_fin(float* __restrict__ lossslot) {
    float S = *lossslot;
    float m = S / 8388608.0f;        // /2^23 exact scaling
    *lossslot = m + 0.25f * m;       // fl(m1 + fl(beta*m2)), m1==m2
}

extern "C" void kernel_launch(void* const* d_in, const int* in_sizes, int n_in,
                              void* d_out, int out_size, void* d_ws, size_t ws_size,
                              hipStream_t stream) {
    const float* z   = (const float*)d_in[0];
    const float* emb = (const float*)d_in[1];
    float* out  = (float*)d_out;
    float* embT = out + EMBT_OFF;
    float* se   = out + SE_OFF;
    float* sz   = out + SZ_OFF;
    float* idxf = out + IDX_OFF;
    float* loss = out + LOSS_OFF;

    k_prep_transpose<<<8192, 256, 0, stream>>>(emb, embT);
    k_se<<<2048, 256, 0, stream>>>(emb, se);
    k_sz<<<128, 256, 0, stream>>>(z, sz);
    k_main<<<2048, 256, 0, stream>>>(z, embT, se, sz, idxf, loss);
    k_out<<<8192, 256, 0, stream>>>(z, emb, idxf, out + ZQ_OFF, loss);
    k_fin<<<1, 1, 0, stream>>>(loss);
}

// Round 9
// 2029.384 us; speedup vs baseline: 1.4114x; 1.0654x over previous
//
#include <hip/hip_runtime.h>

// Problem: VQ-VAE codebook. z [32,256,32,32] f32, emb [8192,256] f32.
// Outputs concatenated in d_out (f32): z_q [8388608], idx [32768] (as float), loss [1].
//
// Scratch layout inside d_out's z_q region (consumed before k_out overwrites it):
//   [0 .. 2097152)        embT  (256 x 8192)   transposed codebook
//   [2097152 .. 2105344)  se    (8192)         ||e_k||^2
//   [2105344 .. 2138112)  sz    (32768)        ||z_n||^2
#define ZQ_OFF   0
#define EMBT_OFF 0
#define SE_OFF   2097152
#define SZ_OFF   2105344
#define IDX_OFF  8388608
#define LOSS_OFF 8421376

// ---- transpose emb -> embT[d][k] (coalesced writes, scattered reads; 8 MB, tiny)
__global__ void k_prep_transpose(const float* __restrict__ emb, float* __restrict__ embT) {
    int u = blockIdx.x * 256 + threadIdx.x;      // 0 .. 2M, grid = 8192 blocks
    int d = u >> 13;
    int k = u & 8191;
    embT[u] = emb[(size_t)k * 256 + d];
}

// ---- se[k] = sum(emb[k]^2)  (order-insensitive; wave per code, butterfly reduce)
__global__ void k_se(const float* __restrict__ emb, float* __restrict__ se) {
    int w    = (blockIdx.x * 256 + threadIdx.x) >> 6;   // code id
    int lane = threadIdx.x & 63;
    float4 v = *(const float4*)(emb + (size_t)w * 256 + lane * 4);
    float s = v.x * v.x + v.y * v.y + v.z * v.z + v.w * v.w;
    #pragma unroll
    for (int off = 1; off < 64; off <<= 1) s += __shfl_xor(s, off);
    if (lane == 0) se[w] = s;
}

// ---- sz[n] = sum over c of z[b][c][hw]^2 (order-insensitive: same-binade shift invariance)
__global__ void k_sz(const float* __restrict__ z, float* __restrict__ sz) {
    int n  = blockIdx.x * 256 + threadIdx.x;  // grid = 128 blocks
    int b  = n >> 10, hw = n & 1023;
    const float* zp = z + (size_t)b * 262144 + hw;
    float acc = 0.f;
    #pragma unroll 8
    for (int c = 0; c < 256; ++c) { float v = zp[(size_t)c << 10]; acc += v * v; }
    sz[n] = acc;
}

// 128 FMAs for one d: 16 rows (4 float4 z, broadcast) x 8 codes (2 float4 ef)
#define FMA_BLOCK(Z, E0, E1) do {                                        \
    _Pragma("unroll")                                                     \
    for (int i_ = 0; i_ < 4; ++i_) {                                      \
        _Pragma("unroll")                                                 \
        for (int q_ = 0; q_ < 4; ++q_) {                                  \
            const float zx_ = ((const float*)&(Z)[i_])[q_];               \
            const int rr_ = i_ * 4 + q_;                                  \
            acc[rr_][0] = fmaf(zx_, (E0).x, acc[rr_][0]);                 \
            acc[rr_][1] = fmaf(zx_, (E0).y, acc[rr_][1]);                 \
            acc[rr_][2] = fmaf(zx_, (E0).z, acc[rr_][2]);                 \
            acc[rr_][3] = fmaf(zx_, (E0).w, acc[rr_][3]);                 \
            acc[rr_][4] = fmaf(zx_, (E1).x, acc[rr_][4]);                 \
            acc[rr_][5] = fmaf(zx_, (E1).y, acc[rr_][5]);                 \
            acc[rr_][6] = fmaf(zx_, (E1).z, acc[rr_][6]);                 \
            acc[rr_][7] = fmaf(zx_, (E1).w, acc[rr_][7]);                 \
        }                                                                 \
    }                                                                     \
} while (0)

// ---- main: exact-f32-replica distance + argmin.
// 256 thr = 4 waves; 16 rows/block; grid 2048. All waves cover all 16 rows (R=16/thread);
// waves split codes 4-ways within a 2048-code tile: wave w owns w*512..+511, lane j owns
// 8 codes. Per d: 4 broadcast ds_read_b128 (z) + 2 global float4 (ef) per 128 FMA ->
// L1 port 0.5, LDS pipe 0.75, FMA the only saturated pipe. BOTH z and ef software-
// pipelined one d ahead (A/B register rotation): the end-of-iteration waits find data
// already arrived, so per-wave stall ~0 and 2 waves/SIMD saturate the issue port.
// Per-tile argmin folded into LDS cwd/cwk (full lowest-k tie-break).
// d_nk = fl( fl(sz_n + se_k) - 2*m_nk ),  m = sequential fmaf chain over d=0..255 (BLAS order)
__global__ __launch_bounds__(256, 2) void k_main(
    const float* __restrict__ z, const float* __restrict__ embT,
    const float* __restrict__ se, const float* __restrict__ sz,
    float* __restrict__ idxf, float* __restrict__ lossslot) {
    __shared__ float ztT[257][16];        // [d][row]; pad row 256 absorbs d=254's d+2 prefetch
    __shared__ float szs[16];
    __shared__ float cwd[4][16];          // [codegrp][row] best distance
    __shared__ int   cwk[4][16];          // matching code id
    const int tid = threadIdx.x;
    const int blk = blockIdx.x;           // grid = 2048
    const int n0  = blk * 16;
    const int b   = n0 >> 10, hw0 = n0 & 1023;

    // stage z tile transposed: ztT[c][n]; coalesced global reads over n;
    // LDS writes 2 lanes/bank (free)
    {
        const int n  = tid & 15;
        const int cg = tid >> 4;                        // 0..15
        const float* zp = z + (size_t)b * 262144 + hw0 + n;
        #pragma unroll
        for (int cc = 0; cc < 256; cc += 16)
            ztT[cc + cg][n] = zp[(size_t)(cc + cg) << 10];
        if (tid < 16) szs[tid] = sz[n0 + tid];
        if (tid < 64) { (&cwd[0][0])[tid] = 3.4e38f; (&cwk[0][0])[tid] = 0; }
    }
    __syncthreads();

    const int w = tid >> 6;       // wave 0..3 -> code quarter w*512 within each tile
    const int j = tid & 63;       // lane -> 8 codes

    for (int tile = 0; tile < 4; ++tile) {
        const int c0 = tile * 2048 + w * 512 + j * 8;
        const float* ep = embT + c0;

        float acc[16][8];
        #pragma unroll
        for (int rr = 0; rr < 16; ++rr)
            #pragma unroll
            for (int c = 0; c < 8; ++c) acc[rr][c] = 0.f;

        // preload d=0 into A (z broadcast reads + ef)
        float4 zA[4], zB[4];
        #pragma unroll
        for (int i = 0; i < 4; ++i) zA[i] = *(const float4*)&ztT[0][i * 4];
        float4 eA0 = *(const float4*)(ep);
        float4 eA1 = *(const float4*)(ep + 4);

        #pragma unroll 1
        for (int d = 0; d < 256; d += 2) {
            // load d+1 into B
            const float* e1p = ep + (size_t)(d + 1) * 8192;
            float4 eB0 = *(const float4*)(e1p);
            float4 eB1 = *(const float4*)(e1p + 4);
            #pragma unroll
            for (int i = 0; i < 4; ++i) zB[i] = *(const float4*)&ztT[d + 1][i * 4];
            // compute d (held in A)
            FMA_BLOCK(zA, eA0, eA1);
            // load d+2 into A (d=254: ztT[256] pad row / embT+2M = se region; never used)
            const float* e2p = ep + (size_t)(d + 2) * 8192;
            eA0 = *(const float4*)(e2p);
            eA1 = *(const float4*)(e2p + 4);
            #pragma unroll
            for (int i = 0; i < 4; ++i) zA[i] = *(const float4*)&ztT[d + 2][i * 4];
            // compute d+1 (held in B)
            FMA_BLOCK(zB, eB0, eB1);
        }

        // epilogue: dq = fl( fl(sz+se) - 2m ); codes ascending; strict < keeps first min
        const float4 seA = *(const float4*)(se + c0);
        const float4 seB = *(const float4*)(se + c0 + 4);
        #pragma unroll
        for (int rr = 0; rr < 16; ++rr) {
            const float szv = szs[rr];
            float bd = 3.4e38f; int bk = 0;
            #pragma unroll
            for (int c = 0; c < 8; ++c) {
                const float sek = (c < 4) ? ((const float*)&seA)[c]
                                          : ((const float*)&seB)[c - 4];
                float A  = szv + sek;
                float dq = A - 2.0f * acc[rr][c];
                if (dq < bd) { bd = dq; bk = c0 + c; }
            }
            // butterfly across 64 lanes; tie-break lowest k
            #pragma unroll
            for (int off = 1; off < 64; off <<= 1) {
                float od = __shfl_xor(bd, off);
                int   ok = __shfl_xor(bk, off);
                if (od < bd || (od == bd && ok < bk)) { bd = od; bk = ok; }
            }
            if (j == 0) {
                float pd = cwd[w][rr]; int pk = cwk[w][rr];
                if (bd < pd || (bd == pd && bk < pk)) { cwd[w][rr] = bd; cwk[w][rr] = bk; }
            }
        }
    }
    __syncthreads();
    // merge the 4 code-group partials per row with full (d,k) tie-break
    if (tid < 16) {
        float d = cwd[0][tid]; int k = cwk[0][tid];
        #pragma unroll
        for (int ww = 1; ww < 4; ++ww) {
            float od = cwd[ww][tid]; int ok = cwk[ww][tid];
            if (od < d || (od == d && ok < k)) { d = od; k = ok; }
        }
        idxf[n0 + tid] = (float)k;
    }
    if (blk == 0 && tid == 0) *lossslot = 0.f;   // init loss accumulator (runs before k_out)
}

// ---- z_q (STE-exact) + loss partial sums
__global__ void k_out(const float* __restrict__ z, const float* __restrict__ emb,
                      const float* __restrict__ idxf, float* __restrict__ zq,
                      float* __restrict__ lossslot) {
    int u   = blockIdx.x * 256 + threadIdx.x;   // grid = 8192 blocks (2M threads)
    int cc4 = u >> 15;                          // 0..63 (uniform per block)
    int n   = u & 32767;
    int b   = n >> 10, hw = n & 1023;
    int k   = (int)idxf[n];
    const float4 q4 = *(const float4*)(emb + (size_t)k * 256 + cc4 * 4);
    float ls = 0.f;
    #pragma unroll
    for (int c = 0; c < 4; ++c) {
        size_t zi = (size_t)b * 262144 + (size_t)(cc4 * 4 + c) * 1024 + hw;
        float zv   = z[zi];
        float qv   = ((const float*)&q4)[c];
        float diff = qv - zv;        // fl(q - z)
        zq[zi]     = zv + diff;      // fl(z + fl(q - z))  == reference STE output
        ls += diff * diff;
    }
    #pragma unroll
    for (int off = 1; off < 64; off <<= 1) ls += __shfl_xor(ls, off);
    if ((threadIdx.x & 63) == 0) atomicAdd(lossslot, ls);
}

__global__ void k_fin(float* __restrict__ lossslot) {
    float S = *lossslot;
    float m = S / 8388608.0f;        // /2^23 exact scaling
    *lossslot = m + 0.25f * m;       // fl(m1 + fl(beta*m2)), m1==m2
}

extern "C" void kernel_launch(void* const* d_in, const int* in_sizes, int n_in,
                              void* d_out, int out_size, void* d_ws, size_t ws_size,
                              hipStream_t stream) {
    const float* z   = (const float*)d_in[0];
    const float* emb = (const float*)d_in[1];
    float* out  = (float*)d_out;
    float* embT = out + EMBT_OFF;
    float* se   = out + SE_OFF;
    float* sz   = out + SZ_OFF;
    float* idxf = out + IDX_OFF;
    float* loss = out + LOSS_OFF;

    k_prep_transpose<<<8192, 256, 0, stream>>>(emb, embT);
    k_se<<<2048, 256, 0, stream>>>(emb, se);
    k_sz<<<128, 256, 0, stream>>>(z, sz);
    k_main<<<2048, 256, 0, stream>>>(z, embT, se, sz, idxf, loss);
    k_out<<<8192, 256, 0, stream>>>(z, emb, idxf, out + ZQ_OFF, loss);
    k_fin<<<1, 1, 0, stream>>>(loss);
}